// Round 4
// baseline (1016.634 us; speedup 1.0000x reference)
//
#include <hip/hip_runtime.h>

typedef float f2 __attribute__((ext_vector_type(2)));

#define TT 2048
#define BB 512
#define II 10
#define HH 20

// One wave (64 lanes) per (direction, batch-sample) sequence.
// Lane j (j<20) computes ALL FOUR gates (i,f,g,o) for hidden unit j
// (rows j, 20+j, 40+j, 60+j). The c/h update is fully lane-local.
// The h broadcast is done with 20x v_readlane into SGPRs -> the recurrence
// consumes h as wave-uniform scalar pairs. NO LDS, NO barriers, NO shuffles:
// the whole timestep is a pure register dataflow.
__global__ __launch_bounds__(64) void lstm_bidir(
    const float* __restrict__ x,
    const float* __restrict__ w_ih_f, const float* __restrict__ w_hh_f,
    const float* __restrict__ b_ih_f, const float* __restrict__ b_hh_f,
    const float* __restrict__ w_ih_r, const float* __restrict__ w_hh_r,
    const float* __restrict__ b_ih_r, const float* __restrict__ b_hh_r,
    float* __restrict__ out)
{
    const int lane = threadIdx.x;
    const int blk  = blockIdx.x;
    const int dir  = blk >> 9;     // 0 = forward, 1 = reverse
    const int s    = blk & 511;    // batch sample

    const float* __restrict__ w_ih = dir ? w_ih_r : w_ih_f;
    const float* __restrict__ w_hh = dir ? w_hh_r : w_hh_f;
    const float* __restrict__ b_ih = dir ? b_ih_r : b_ih_f;
    const float* __restrict__ b_hh = dir ? b_hh_r : b_hh_f;

    const bool valid = (lane < HH);
    const int  j     = valid ? lane : (HH - 1);     // clamp keeps loads in-bounds

    // Gate rows for hidden unit j (PyTorch order i,f,g,o), float2-packed.
    f2 whh[4][10], wih[4][5];
    float bs[4];
#pragma unroll
    for (int g = 0; g < 4; ++g) {
        const int r = g * HH + j;
#pragma unroll
        for (int k = 0; k < 10; ++k) whh[g][k] = *(const f2*)(w_hh + r * HH + 2 * k);
#pragma unroll
        for (int k = 0; k < 5; ++k)  wih[g][k] = *(const f2*)(w_ih + r * II + 2 * k);
        bs[g] = b_ih[r] + b_hh[r];
    }

    const int t0    = dir ? (TT - 1) : 0;
    const int xstep = dir ? -(BB * II) : (BB * II);
    const int ostep = dir ? -(BB * 2 * HH) : (BB * 2 * HH);

    int xoff  = (t0 * BB + s) * II;
    int xoffn = xoff + xstep;
    int ooff  = (t0 * BB + s) * (2 * HH) + dir * HH + j;

    // Prime x double-buffer (t0, t0+1)
    f2 xv[5], xn[5];
#pragma unroll
    for (int k = 0; k < 5; ++k) xv[k] = *(const f2*)(x + xoff  + 2 * k);
#pragma unroll
    for (int k = 0; k < 5; ++k) xn[k] = *(const f2*)(x + xoffn + 2 * k);

    // x-projection + bias for step t0 (off the recurrent critical path)
    float xproj[4];
#pragma unroll
    for (int g = 0; g < 4; ++g) {
        f2 p = wih[g][0] * xv[0];
#pragma unroll
        for (int k = 1; k < 5; ++k) p += wih[g][k] * xv[k];
        xproj[g] = bs[g] + p[0] + p[1];
    }

    float c = 0.0f, h = 0.0f;

#pragma unroll 2
    for (int tt = 0; tt < TT; ++tt) {
        // ---- h broadcast: 20x v_readlane -> wave-uniform scalars (SGPRs) ----
        float hs[HH];
#pragma unroll
        for (int k = 0; k < HH; ++k)
            hs[k] = __builtin_bit_cast(float,
                      __builtin_amdgcn_readlane(__builtin_bit_cast(int, h), k));

        // ---- recurrent dots: 4 gates x 10 pk-FMA ----
        f2 a0[4], a1[4];
#pragma unroll
        for (int g = 0; g < 4; ++g) { a0[g] = f2{0.f, 0.f}; a1[g] = f2{0.f, 0.f}; }
#pragma unroll
        for (int k = 0; k < 5; ++k) {
            f2 lo; lo[0] = hs[4 * k];     lo[1] = hs[4 * k + 1];
            f2 hi; hi[0] = hs[4 * k + 2]; hi[1] = hs[4 * k + 3];
#pragma unroll
            for (int g = 0; g < 4; ++g) {
                a0[g] += whh[g][2 * k]     * lo;
                a1[g] += whh[g][2 * k + 1] * hi;
            }
        }
        float v[4];
#pragma unroll
        for (int g = 0; g < 4; ++g) {
            const f2 a = a0[g] + a1[g];
            v[g] = xproj[g] + a[0] + a[1];
        }

        // ---- activations (lane-local, 4 independent chains) ----
        const float ig = __builtin_amdgcn_rcpf(1.0f + __expf(-v[0]));                 // sigmoid i
        const float fg = __builtin_amdgcn_rcpf(1.0f + __expf(-v[1]));                 // sigmoid f
        const float gg = __builtin_fmaf(2.0f,
                          __builtin_amdgcn_rcpf(1.0f + __expf(-2.0f * v[2])), -1.0f); // tanh g
        const float og = __builtin_amdgcn_rcpf(1.0f + __expf(-v[3]));                 // sigmoid o

        // ---- lane-local state update ----
        c = __builtin_fmaf(fg, c, ig * gg);
        const float th = __builtin_fmaf(2.0f,
                          __builtin_amdgcn_rcpf(1.0f + __expf(-2.0f * c)), -1.0f);    // tanh c
        h = og * th;

        if (valid) out[ooff] = h;

        // ---- advance x pipeline (independent of h chain) ----
#pragma unroll
        for (int k = 0; k < 5; ++k) xv[k] = xn[k];
        xoff  = xoffn;
        xoffn = (tt < TT - 2) ? (xoff + xstep) : xoff;
#pragma unroll
        for (int k = 0; k < 5; ++k) xn[k] = *(const f2*)(x + xoffn + 2 * k);

        // x-projection for step tt+1
#pragma unroll
        for (int g = 0; g < 4; ++g) {
            f2 p = wih[g][0] * xv[0];
#pragma unroll
            for (int k = 1; k < 5; ++k) p += wih[g][k] * xv[k];
            xproj[g] = bs[g] + p[0] + p[1];
        }

        ooff += ostep;
    }
}

extern "C" void kernel_launch(void* const* d_in, const int* in_sizes, int n_in,
                              void* d_out, int out_size, void* d_ws, size_t ws_size,
                              hipStream_t stream) {
    const float* xp     = (const float*)d_in[0];
    const float* w_ih_f = (const float*)d_in[1];
    const float* w_hh_f = (const float*)d_in[2];
    const float* b_ih_f = (const float*)d_in[3];
    const float* b_hh_f = (const float*)d_in[4];
    const float* w_ih_r = (const float*)d_in[5];
    const float* w_hh_r = (const float*)d_in[6];
    const float* b_ih_r = (const float*)d_in[7];
    const float* b_hh_r = (const float*)d_in[8];
    float* outp = (float*)d_out;

    hipLaunchKernelGGL(lstm_bidir, dim3(1024), dim3(64), 0, stream,
                       xp, w_ih_f, w_hh_f, b_ih_f, b_hh_f,
                       w_ih_r, w_hh_r, b_ih_r, b_hh_r, outp);
}

// Round 5
// 618.645 us; speedup vs baseline: 1.6433x; 1.6433x over previous
//
#include <hip/hip_runtime.h>

typedef float f2 __attribute__((ext_vector_type(2)));
typedef float f4 __attribute__((ext_vector_type(4)));

#define TT 2048
#define BB 512
#define II 10
#define HH 20

// One wave (64 lanes) per (direction, batch-sample) sequence.
// Lane j (j<20) computes ALL FOUR gates (i,f,g,o) for hidden unit j
// (rows j, 20+j, 40+j, 60+j). The c/h update is fully lane-local; the only
// cross-lane op per step is the 20-float h broadcast via LDS (wave-local,
// no __syncthreads). x is prefetched 3 steps deep so the per-step 40B
// x-load (fresh HBM line every step, ~900cy) is fully latency-hidden.
__global__ __launch_bounds__(64) void lstm_bidir(
    const float* __restrict__ x,
    const float* __restrict__ w_ih_f, const float* __restrict__ w_hh_f,
    const float* __restrict__ b_ih_f, const float* __restrict__ b_hh_f,
    const float* __restrict__ w_ih_r, const float* __restrict__ w_hh_r,
    const float* __restrict__ b_ih_r, const float* __restrict__ b_hh_r,
    float* __restrict__ out)
{
    const int lane = threadIdx.x;
    const int blk  = blockIdx.x;
    const int dir  = blk >> 9;     // 0 = forward, 1 = reverse
    const int s    = blk & 511;    // batch sample

    const float* __restrict__ w_ih = dir ? w_ih_r : w_ih_f;
    const float* __restrict__ w_hh = dir ? w_hh_r : w_hh_f;
    const float* __restrict__ b_ih = dir ? b_ih_r : b_ih_f;
    const float* __restrict__ b_hh = dir ? b_hh_r : b_hh_f;

    const bool valid = (lane < HH);
    const int  j     = valid ? lane : (HH - 1);     // clamp keeps loads in-bounds

    // Gate rows for hidden unit j (PyTorch order i,f,g,o), float2-packed.
    f2 whh[4][10], wih[4][5];
    float bs[4];
#pragma unroll
    for (int g = 0; g < 4; ++g) {
        const int r = g * HH + j;
#pragma unroll
        for (int k = 0; k < 10; ++k) whh[g][k] = *(const f2*)(w_hh + r * HH + 2 * k);
#pragma unroll
        for (int k = 0; k < 5; ++k)  wih[g][k] = *(const f2*)(w_ih + r * II + 2 * k);
        bs[g] = b_ih[r] + b_hh[r];
    }

    __shared__ f4 hlds[5];   // h[20] broadcast buffer (one sample per block)
    if (valid) ((float*)hlds)[lane] = 0.0f;
    __builtin_amdgcn_wave_barrier();

    const int t0    = dir ? (TT - 1) : 0;
    const int xstep = dir ? -(BB * II) : (BB * II);
    const int ostep = dir ? -(BB * 2 * HH) : (BB * 2 * HH);

    const int xbase = (t0 * BB + s) * II;
    int ooff = (t0 * BB + s) * (2 * HH) + dir * HH + j;

    // ---- prime the 3-deep x pipeline ----
    // xproj holds the projection for the CURRENT step t.
    // xb1 = raw x(t+1), xb2 = raw x(t+2); the loop issues the load for t+3.
    f2 xb1[5], xb2[5];
    float xproj[4];
    {
        f2 x0[5];
#pragma unroll
        for (int k = 0; k < 5; ++k) x0[k]  = *(const f2*)(x + xbase + 2 * k);
#pragma unroll
        for (int k = 0; k < 5; ++k) xb1[k] = *(const f2*)(x + xbase + xstep + 2 * k);
#pragma unroll
        for (int k = 0; k < 5; ++k) xb2[k] = *(const f2*)(x + xbase + 2 * xstep + 2 * k);
#pragma unroll
        for (int g = 0; g < 4; ++g) {
            f2 p = wih[g][0] * x0[0];
#pragma unroll
            for (int k = 1; k < 5; ++k) p += wih[g][k] * x0[k];
            xproj[g] = bs[g] + p[0] + p[1];
        }
    }
    int xoff3 = xbase + 3 * xstep;   // offset of t+3 (first load issued at tt=0)

    // Prime the h broadcast (zeros)
    f4 hb[5];
#pragma unroll
    for (int k = 0; k < 5; ++k) hb[k] = hlds[k];

    float c = 0.0f, h = 0.0f;

#pragma unroll 3
    for (int tt = 0; tt < TT; ++tt) {
        // ---- issue x load for t+3 as early as possible (max vmcnt slack) ----
        f2 xb3[5];
#pragma unroll
        for (int k = 0; k < 5; ++k) xb3[k] = *(const f2*)(x + xoff3 + 2 * k);
        xoff3 = (tt < TT - 4) ? (xoff3 + xstep) : xoff3;   // clamp: stays in-bounds

        // ---- recurrent dots: 4 gates x 10 pk-FMA (depends on hb) ----
        f2 a0[4], a1[4];
#pragma unroll
        for (int g = 0; g < 4; ++g) { a0[g] = f2{0.f, 0.f}; a1[g] = f2{0.f, 0.f}; }
#pragma unroll
        for (int k = 0; k < 5; ++k) {
            const f4 hv = hb[k];
            f2 lo; lo[0] = hv[0]; lo[1] = hv[1];
            f2 hi; hi[0] = hv[2]; hi[1] = hv[3];
#pragma unroll
            for (int g = 0; g < 4; ++g) {
                a0[g] += whh[g][2 * k]     * lo;
                a1[g] += whh[g][2 * k + 1] * hi;
            }
        }
        float v[4];
#pragma unroll
        for (int g = 0; g < 4; ++g) {
            const f2 a = a0[g] + a1[g];
            v[g] = xproj[g] + a[0] + a[1];
        }

        // ---- activations (lane-local, 4 independent chains) ----
        const float ig = __builtin_amdgcn_rcpf(1.0f + __expf(-v[0]));                 // sigmoid i
        const float fg = __builtin_amdgcn_rcpf(1.0f + __expf(-v[1]));                 // sigmoid f
        const float gg = __builtin_fmaf(2.0f,
                          __builtin_amdgcn_rcpf(1.0f + __expf(-2.0f * v[2])), -1.0f); // tanh g
        const float og = __builtin_amdgcn_rcpf(1.0f + __expf(-v[3]));                 // sigmoid o

        // ---- lane-local state update ----
        c = __builtin_fmaf(fg, c, ig * gg);
        const float th = __builtin_fmaf(2.0f,
                          __builtin_amdgcn_rcpf(1.0f + __expf(-2.0f * c)), -1.0f);    // tanh c
        h = og * th;

        if (valid) {
            ((float*)hlds)[lane] = h;    // wave-local write, no barrier needed
            out[ooff] = h;
        }
        __builtin_amdgcn_wave_barrier();

        // ---- broadcast read for next step (latency covered by xproj below) ----
#pragma unroll
        for (int k = 0; k < 5; ++k) hb[k] = hlds[k];

        // ---- x-projection for step t+1 from xb1 (loaded 2 iters ago) ----
#pragma unroll
        for (int g = 0; g < 4; ++g) {
            f2 p = wih[g][0] * xb1[0];
#pragma unroll
            for (int k = 1; k < 5; ++k) p += wih[g][k] * xb1[k];
            xproj[g] = bs[g] + p[0] + p[1];
        }

        // ---- rotate the pipeline (renamed away by unroll 3) ----
#pragma unroll
        for (int k = 0; k < 5; ++k) { xb1[k] = xb2[k]; xb2[k] = xb3[k]; }

        ooff += ostep;
    }
}

extern "C" void kernel_launch(void* const* d_in, const int* in_sizes, int n_in,
                              void* d_out, int out_size, void* d_ws, size_t ws_size,
                              hipStream_t stream) {
    const float* xp     = (const float*)d_in[0];
    const float* w_ih_f = (const float*)d_in[1];
    const float* w_hh_f = (const float*)d_in[2];
    const float* b_ih_f = (const float*)d_in[3];
    const float* b_hh_f = (const float*)d_in[4];
    const float* w_ih_r = (const float*)d_in[5];
    const float* w_hh_r = (const float*)d_in[6];
    const float* b_ih_r = (const float*)d_in[7];
    const float* b_hh_r = (const float*)d_in[8];
    float* outp = (float*)d_out;

    hipLaunchKernelGGL(lstm_bidir, dim3(1024), dim3(64), 0, stream,
                       xp, w_ih_f, w_hh_f, b_ih_f, b_hh_f,
                       w_ih_r, w_hh_r, b_ih_r, b_hh_r, outp);
}